// Round 1
// baseline (1621.273 us; speedup 1.0000x reference)
//
#include <hip/hip_runtime.h>
#include <hip/hip_bf16.h>

typedef __hip_bfloat16 bf16;

#define NVX 117000
#define NEX 468000
#define EMB 300
#define STR 304            // padded row stride for bf16 node buffers (pads zeroed)
#define IN_DIM 768
#define BATCH 4096
#define HID 500

__device__ __forceinline__ float sigmoidf_(float x){ return 1.0f/(1.0f + __expf(-x)); }
__device__ __forceinline__ float us2f(unsigned short u){
  unsigned int v = ((unsigned int)u) << 16;
  return __uint_as_float(v);
}
__device__ __forceinline__ float ldf(const float* p){ return *p; }
__device__ __forceinline__ float ldf(const bf16* p){ return __bfloat162float(*p); }

// ---------------- graph preprocessing ----------------

__global__ void k_deg(const int* __restrict__ erow, int* __restrict__ deg){
  int i = blockIdx.x*blockDim.x + threadIdx.x;
  if (i < NEX) atomicAdd(&deg[erow[i]], 1);
}

__global__ void k_dinv(const int* __restrict__ deg, float* __restrict__ dinv){
  int i = blockIdx.x*blockDim.x + threadIdx.x;
  if (i < NVX){ int d = deg[i]; dinv[i] = d > 0 ? rsqrtf((float)d) : 0.0f; }
}

__global__ __launch_bounds__(1024) void k_scan(const int* __restrict__ deg,
                                               int* __restrict__ rowptr,
                                               int* __restrict__ cursor){
  __shared__ int sc[1024];
  int t = threadIdx.x;
  const int CH = (NVX + 1023)/1024;   // 115
  int lo = t*CH, hi = lo+CH; if (hi > NVX) hi = NVX; if (lo > NVX) lo = NVX;
  int s = 0;
  for (int i=lo;i<hi;++i) s += deg[i];
  sc[t] = s; __syncthreads();
  for (int off=1; off<1024; off<<=1){
    int v = (t>=off) ? sc[t-off] : 0;
    __syncthreads();
    sc[t] += v;
    __syncthreads();
  }
  int run = sc[t] - s;  // exclusive prefix
  for (int i=lo;i<hi;++i){ rowptr[i]=run; cursor[i]=run; run += deg[i]; }
  if (t==1023) rowptr[NVX] = sc[1023];
}

__global__ void k_scatter(const int* __restrict__ erow, const int* __restrict__ ecol,
                          const float* __restrict__ dinv, int* __restrict__ cursor,
                          int* __restrict__ ccol, float* __restrict__ cval){
  int i = blockIdx.x*blockDim.x + threadIdx.x;
  if (i < NEX){
    int r = erow[i], c = ecol[i];
    int p = atomicAdd(&cursor[r], 1);
    ccol[p] = c;
    cval[p] = dinv[r]*dinv[c];
  }
}

// ---------------- spmm: Y[v,:] = sum_e val * X[col(e),:]  (wave per row) ----------------

template<typename T>
__global__ __launch_bounds__(256) void k_spmm(const int* __restrict__ rowptr,
                                              const int* __restrict__ ccol,
                                              const float* __restrict__ cval,
                                              const T* __restrict__ X, int xstride,
                                              bf16* __restrict__ Y){
  int w = (int)((blockIdx.x*blockDim.x + threadIdx.x) >> 6);
  int lane = threadIdx.x & 63;
  if (w >= NVX) return;
  float acc[5] = {0.f,0.f,0.f,0.f,0.f};
  int e0 = rowptr[w], e1 = rowptr[w+1];
  for (int e=e0; e<e1; ++e){
    float v = cval[e];
    const T* xr = X + (size_t)ccol[e]*xstride;
    #pragma unroll
    for (int j=0;j<5;++j){
      int col = lane + 64*j;
      if (col < EMB) acc[j] += v * ldf(xr + col);
    }
  }
  bf16* yr = Y + (size_t)w*STR;
  #pragma unroll
  for (int j=0;j<5;++j){
    int col = lane + 64*j;
    if (col < EMB) yr[col] = __float2bfloat16(acc[j]);
    else if (col < STR) yr[col] = __float2bfloat16(0.0f);
  }
}

// ---------------- node GEMM: C = sigmoid(A @ W), A bf16 [NV,STR], W f32 [300,300] ----------------

__global__ __launch_bounds__(256) void k_gemm_nodes(const bf16* __restrict__ A,
                                                    const float* __restrict__ W,
                                                    bf16* __restrict__ C){
  __shared__ float As[16][64];
  __shared__ float Ws[16][64];
  int tid = threadIdx.x;
  int tx = tid & 15, ty = tid >> 4;
  int row0 = blockIdx.x * 64, n0 = blockIdx.y * 64;
  float acc[4][4] = {};
  int lr = tid >> 2;          // 0..63  (A row within tile)
  int lq = (tid & 3) * 4;     // 0,4,8,12 (k offset)
  int wk = tid >> 4;          // 0..15  (W k within chunk)
  int wc = (tid & 15) * 4;    // 0..60  (W col offset)
  for (int k0 = 0; k0 < STR; k0 += 16){
    int ar = row0 + lr;
    ushort4 av = make_ushort4(0,0,0,0);
    if (ar < NVX) av = *(const ushort4*)(A + (size_t)ar*STR + k0 + lq);
    As[lq+0][lr] = us2f(av.x);
    As[lq+1][lr] = us2f(av.y);
    As[lq+2][lr] = us2f(av.z);
    As[lq+3][lr] = us2f(av.w);
    int kk = k0 + wk;
    #pragma unroll
    for (int i=0;i<4;++i){
      int col = n0 + wc + i;
      Ws[wk][wc+i] = (kk < EMB && col < EMB) ? W[kk*EMB + col] : 0.0f;
    }
    __syncthreads();
    #pragma unroll
    for (int p=0;p<16;++p){
      float ra[4], rb[4];
      #pragma unroll
      for (int i=0;i<4;++i) ra[i] = As[p][ty*4+i];
      #pragma unroll
      for (int j=0;j<4;++j) rb[j] = Ws[p][tx*4+j];
      #pragma unroll
      for (int i=0;i<4;++i)
        #pragma unroll
        for (int j=0;j<4;++j) acc[i][j] += ra[i]*rb[j];
    }
    __syncthreads();
  }
  #pragma unroll
  for (int i=0;i<4;++i){
    int row = row0 + ty*4 + i;
    if (row >= NVX) continue;
    bf16* cr = C + (size_t)row*STR;
    #pragma unroll
    for (int j=0;j<4;++j){
      int col = n0 + tx*4 + j;
      if (col < EMB) cr[col] = __float2bfloat16(sigmoidf_(acc[i][j]));
      else if (col < STR) cr[col] = __float2bfloat16(0.0f);
    }
  }
}

// ---------------- FC1: h1 = sigmoid([H2[node], input] @ Wa + ba) ----------------

__global__ __launch_bounds__(256) void k_fc1(const bf16* __restrict__ H2,
                                             const int* __restrict__ node,
                                             const float* __restrict__ input,
                                             const float* __restrict__ Wa,
                                             const float* __restrict__ ba,
                                             float* __restrict__ h1){
  __shared__ float As[16][64];
  __shared__ float Ws[16][64];
  __shared__ int snode[64];
  int tid = threadIdx.x;
  int tx = tid & 15, ty = tid >> 4;
  int row0 = blockIdx.x*64, n0 = blockIdx.y*64;
  if (tid < 64) snode[tid] = node[row0 + tid];
  __syncthreads();
  float acc[4][4] = {};
  int lr = tid >> 2, lq = (tid & 3) * 4;
  int wk = tid >> 4, wc = (tid & 15) * 4;
  const int K = EMB + IN_DIM;  // 1068
  for (int k0 = 0; k0 < K; k0 += 16){
    int r = row0 + lr;
    const bf16* hrow = H2 + (size_t)snode[lr]*STR;
    #pragma unroll
    for (int i=0;i<4;++i){
      int k = k0 + lq + i;
      float v = 0.0f;
      if (k < EMB) v = __bfloat162float(hrow[k]);
      else if (k < K) v = input[(size_t)r*IN_DIM + (k - EMB)];
      As[lq+i][lr] = v;
    }
    int kk = k0 + wk;
    #pragma unroll
    for (int i=0;i<4;++i){
      int col = n0 + wc + i;
      Ws[wk][wc+i] = (kk < K && col < HID) ? Wa[(size_t)kk*HID + col] : 0.0f;
    }
    __syncthreads();
    #pragma unroll
    for (int p=0;p<16;++p){
      float ra[4], rb[4];
      #pragma unroll
      for (int i=0;i<4;++i) ra[i] = As[p][ty*4+i];
      #pragma unroll
      for (int j=0;j<4;++j) rb[j] = Ws[p][tx*4+j];
      #pragma unroll
      for (int i=0;i<4;++i)
        #pragma unroll
        for (int j=0;j<4;++j) acc[i][j] += ra[i]*rb[j];
    }
    __syncthreads();
  }
  #pragma unroll
  for (int i=0;i<4;++i){
    int row = row0 + ty*4 + i;
    #pragma unroll
    for (int j=0;j<4;++j){
      int col = n0 + tx*4 + j;
      if (col < HID) h1[(size_t)row*HID + col] = sigmoidf_(acc[i][j] + ba[col]);
    }
  }
}

// ---------------- FC2: h2 = sigmoid(h1 @ Wb + bb) ----------------

__global__ __launch_bounds__(256) void k_fc2(const float* __restrict__ h1,
                                             const float* __restrict__ Wb,
                                             const float* __restrict__ bb,
                                             float* __restrict__ h2){
  __shared__ float As[16][64];
  __shared__ float Ws[16][64];
  int tid = threadIdx.x;
  int tx = tid & 15, ty = tid >> 4;
  int row0 = blockIdx.x*64, n0 = blockIdx.y*64;
  float acc[4][4] = {};
  int lr = tid >> 2, lq = (tid & 3) * 4;
  int wk = tid >> 4, wc = (tid & 15) * 4;
  for (int k0 = 0; k0 < HID; k0 += 16){
    int r = row0 + lr;
    #pragma unroll
    for (int i=0;i<4;++i){
      int k = k0 + lq + i;
      As[lq+i][lr] = (k < HID) ? h1[(size_t)r*HID + k] : 0.0f;
    }
    int kk = k0 + wk;
    #pragma unroll
    for (int i=0;i<4;++i){
      int col = n0 + wc + i;
      Ws[wk][wc+i] = (kk < HID && col < HID) ? Wb[(size_t)kk*HID + col] : 0.0f;
    }
    __syncthreads();
    #pragma unroll
    for (int p=0;p<16;++p){
      float ra[4], rb[4];
      #pragma unroll
      for (int i=0;i<4;++i) ra[i] = As[p][ty*4+i];
      #pragma unroll
      for (int j=0;j<4;++j) rb[j] = Ws[p][tx*4+j];
      #pragma unroll
      for (int i=0;i<4;++i)
        #pragma unroll
        for (int j=0;j<4;++j) acc[i][j] += ra[i]*rb[j];
    }
    __syncthreads();
  }
  #pragma unroll
  for (int i=0;i<4;++i){
    int row = row0 + ty*4 + i;
    #pragma unroll
    for (int j=0;j<4;++j){
      int col = n0 + tx*4 + j;
      if (col < HID) h2[(size_t)row*HID + col] = sigmoidf_(acc[i][j] + bb[col]);
    }
  }
}

// ---------------- FC3: out = h2 @ Wc + bc  (wave per batch row) ----------------

__global__ __launch_bounds__(256) void k_fc3(const float* __restrict__ h2,
                                             const float* __restrict__ Wc,
                                             const float* __restrict__ bc,
                                             float* __restrict__ out){
  int w = (int)((blockIdx.x*blockDim.x + threadIdx.x) >> 6);
  int lane = threadIdx.x & 63;
  if (w >= BATCH) return;
  const float* hr = h2 + (size_t)w*HID;
  float a0 = 0.f, a1 = 0.f;
  for (int k = lane; k < HID; k += 64){
    float h = hr[k];
    a0 += h * Wc[k*2+0];
    a1 += h * Wc[k*2+1];
  }
  #pragma unroll
  for (int off = 32; off; off >>= 1){
    a0 += __shfl_down(a0, off);
    a1 += __shfl_down(a1, off);
  }
  if (lane == 0){
    out[w*2+0] = a0 + bc[0];
    out[w*2+1] = a1 + bc[1];
  }
}

// ---------------- launch ----------------

extern "C" void kernel_launch(void* const* d_in, const int* in_sizes, int n_in,
                              void* d_out, int out_size, void* d_ws, size_t ws_size,
                              hipStream_t stream){
  const float* input = (const float*)d_in[0];
  const int*   node  = (const int*)d_in[1];
  const int*   erow  = (const int*)d_in[2];
  const int*   ecol  = (const int*)d_in[3];
  const float* H0    = (const float*)d_in[4];
  const float* W1    = (const float*)d_in[5];
  const float* W2    = (const float*)d_in[6];
  const float* Wa    = (const float*)d_in[7];
  const float* ba    = (const float*)d_in[8];
  const float* Wb    = (const float*)d_in[9];
  const float* bb    = (const float*)d_in[10];
  const float* Wc    = (const float*)d_in[11];
  const float* bc    = (const float*)d_in[12];

  char* p = (char*)d_ws;
  auto alloc = [&](size_t bytes)->char*{ char* r = p; p += (bytes + 255) & ~(size_t)255; return r; };
  int*   deg    = (int*)  alloc((size_t)NVX*4);
  float* dinv   = (float*)alloc((size_t)NVX*4);
  int*   rowptr = (int*)  alloc((size_t)(NVX+1)*4);
  int*   cursor = (int*)  alloc((size_t)NVX*4);
  int*   ccol   = (int*)  alloc((size_t)NEX*4);
  float* cval   = (float*)alloc((size_t)NEX*4);
  bf16*  G      = (bf16*) alloc((size_t)NVX*STR*2);
  bf16*  Hb     = (bf16*) alloc((size_t)NVX*STR*2);
  float* h1     = (float*)alloc((size_t)BATCH*HID*4);
  float* h2     = (float*)alloc((size_t)BATCH*HID*4);

  hipMemsetAsync(deg, 0, (size_t)NVX*4, stream);
  k_deg    <<<(NEX+255)/256, 256, 0, stream>>>(erow, deg);
  k_dinv   <<<(NVX+255)/256, 256, 0, stream>>>(deg, dinv);
  k_scan   <<<1, 1024, 0, stream>>>(deg, rowptr, cursor);
  k_scatter<<<(NEX+255)/256, 256, 0, stream>>>(erow, ecol, dinv, cursor, ccol, cval);

  // G1 = LM @ H0 ; H1 = sigmoid(G1 @ W1)   (associativity: LM@(H0@W1) == (LM@H0)@W1)
  k_spmm<float><<<(NVX+3)/4, 256, 0, stream>>>(rowptr, ccol, cval, H0, EMB, G);
  k_gemm_nodes <<<dim3((NVX+63)/64, (EMB+63)/64), 256, 0, stream>>>(G, W1, Hb);
  // G2 = LM @ H1 ; H2 = sigmoid(G2 @ W2)
  k_spmm<bf16> <<<(NVX+3)/4, 256, 0, stream>>>(rowptr, ccol, cval, Hb, STR, G);
  k_gemm_nodes <<<dim3((NVX+63)/64, (EMB+63)/64), 256, 0, stream>>>(G, W2, Hb);

  k_fc1<<<dim3(BATCH/64, (HID+63)/64), 256, 0, stream>>>(Hb, node, input, Wa, ba, h1);
  k_fc2<<<dim3(BATCH/64, (HID+63)/64), 256, 0, stream>>>(h1, Wb, bb, h2);
  k_fc3<<<BATCH/4, 256, 0, stream>>>(h2, Wc, bc, (float*)d_out);
}

// Round 2
// 1105.924 us; speedup vs baseline: 1.4660x; 1.4660x over previous
//
#include <hip/hip_runtime.h>
#include <hip/hip_bf16.h>

typedef __hip_bfloat16 bf16;

#define NVX 117000
#define NVR 117120         // rows padded to multiple of 128 (= 915*128)
#define NEX 468000
#define EMB 300
#define STR 320            // padded K/row stride for bf16 node buffers (pads zeroed)
#define NPAD 384           // padded N for node GEMM (3 tiles of 128)
#define IN_DIM 768
#define BATCH 4096
#define HID 500

typedef __attribute__((ext_vector_type(8))) short frag8;   // 8 bf16 (4 VGPRs)
typedef __attribute__((ext_vector_type(4))) float f32x4;   // 4 fp32 acc

__device__ __forceinline__ float sigmoidf_(float x){ return 1.0f/(1.0f + __expf(-x)); }
__device__ __forceinline__ float ldf(const float* p){ return *p; }
__device__ __forceinline__ float ldf(const bf16* p){ return __bfloat162float(*p); }

__device__ __forceinline__ void gload_lds16(const bf16* g, bf16* l){
  __builtin_amdgcn_global_load_lds((const __attribute__((address_space(1))) void*)g,
                                   (__attribute__((address_space(3))) void*)l, 16, 0, 0);
}

// ---------------- graph preprocessing ----------------

__global__ void k_deg(const int* __restrict__ erow, int* __restrict__ deg){
  int i = blockIdx.x*blockDim.x + threadIdx.x;
  if (i < NEX) atomicAdd(&deg[erow[i]], 1);
}

__global__ void k_dinv(const int* __restrict__ deg, float* __restrict__ dinv){
  int i = blockIdx.x*blockDim.x + threadIdx.x;
  if (i < NVX){ int d = deg[i]; dinv[i] = d > 0 ? rsqrtf((float)d) : 0.0f; }
}

__global__ __launch_bounds__(1024) void k_scan(const int* __restrict__ deg,
                                               int* __restrict__ rowptr,
                                               int* __restrict__ cursor){
  __shared__ int sc[1024];
  int t = threadIdx.x;
  const int CH = (NVX + 1023)/1024;   // 115
  int lo = t*CH, hi = lo+CH; if (hi > NVX) hi = NVX; if (lo > NVX) lo = NVX;
  int s = 0;
  for (int i=lo;i<hi;++i) s += deg[i];
  sc[t] = s; __syncthreads();
  for (int off=1; off<1024; off<<=1){
    int v = (t>=off) ? sc[t-off] : 0;
    __syncthreads();
    sc[t] += v;
    __syncthreads();
  }
  int run = sc[t] - s;  // exclusive prefix
  for (int i=lo;i<hi;++i){ rowptr[i]=run; cursor[i]=run; run += deg[i]; }
  if (t==1023) rowptr[NVX] = sc[1023];
}

__global__ void k_scatter(const int* __restrict__ erow, const int* __restrict__ ecol,
                          const float* __restrict__ dinv, int* __restrict__ cursor,
                          int* __restrict__ ccol, float* __restrict__ cval){
  int i = blockIdx.x*blockDim.x + threadIdx.x;
  if (i < NEX){
    int r = erow[i], c = ecol[i];
    int p = atomicAdd(&cursor[r], 1);
    ccol[p] = c;
    cval[p] = dinv[r]*dinv[c];
  }
}

// W (f32, [300,300] k-major) -> Wt (bf16, [NPAD][STR] n-major, zero-padded)
__global__ void k_prepW(const float* __restrict__ W, bf16* __restrict__ Wt){
  int i = blockIdx.x*blockDim.x + threadIdx.x;
  if (i >= NPAD*STR) return;
  int n = i / STR, k = i % STR;
  float v = (n < EMB && k < EMB) ? W[k*EMB + n] : 0.0f;
  Wt[i] = __float2bfloat16(v);
}

// ---------------- spmm: Y[v,:] = sum_e val * X[col(e),:]  (wave per row) ----------------

template<typename T>
__global__ __launch_bounds__(256) void k_spmm(const int* __restrict__ rowptr,
                                              const int* __restrict__ ccol,
                                              const float* __restrict__ cval,
                                              const T* __restrict__ X, int xstride,
                                              bf16* __restrict__ Y){
  int w = (int)((blockIdx.x*blockDim.x + threadIdx.x) >> 6);
  int lane = threadIdx.x & 63;
  if (w >= NVR) return;
  bf16* yr = Y + (size_t)w*STR;
  if (w >= NVX){   // pad rows: keep zero so MFMA A-tiles read clean data
    #pragma unroll
    for (int j=0;j<5;++j) yr[lane + 64*j] = __float2bfloat16(0.0f);
    return;
  }
  float acc[5] = {0.f,0.f,0.f,0.f,0.f};
  int e0 = rowptr[w], e1 = rowptr[w+1];
  for (int e=e0; e<e1; ++e){
    float v = cval[e];
    const T* xr = X + (size_t)ccol[e]*xstride;
    #pragma unroll
    for (int j=0;j<5;++j){
      int col = lane + 64*j;
      if (col < EMB) acc[j] += v * ldf(xr + col);
    }
  }
  #pragma unroll
  for (int j=0;j<5;++j){
    int col = lane + 64*j;
    yr[col] = __float2bfloat16(col < EMB ? acc[j] : 0.0f);
  }
}

// ---------------- node GEMM (MFMA): C = sigmoid(A @ W), A bf16 [NVR,STR], Wt bf16 [NPAD][STR] ----------------
// m97 structure: 128x128 tile, 4 waves in 2x2, each wave 4x4 frags of 16x16x32 bf16.
// grid = (NPAD/128, NVR/128): x fastest => 3 n-tiles of one row-tile run back-to-back (A stays in L2).

__global__ __launch_bounds__(256) void k_gemm_mfma(const bf16* __restrict__ A,
                                                   const bf16* __restrict__ Wt,
                                                   bf16* __restrict__ C){
  __shared__ bf16 As[128*32];
  __shared__ bf16 Bs[128*32];
  const int tid  = threadIdx.x;
  const int wv   = tid >> 6;
  const int lane = tid & 63;
  const int row0 = blockIdx.y * 128;
  const int n0   = blockIdx.x * 128;
  const int wm = wv & 1, wn = wv >> 1;

  f32x4 acc[4][4];
  #pragma unroll
  for (int i=0;i<4;++i)
    #pragma unroll
    for (int j=0;j<4;++j) acc[i][j] = (f32x4)(0.0f);

  const int srow = lane >> 2;     // 0..15 staging row within wave stripe
  const int schk = lane & 3;      // 16B chunk within 64B (=32 bf16) row

  const int fr = lane & 15;       // fragment row/col index
  const int fq = lane >> 4;       // quad -> k offset = fq*8

  for (int k0 = 0; k0 < STR; k0 += 32){
    // stage A tile 128x32 and B tile 128x32 (Wt is n-major so same pattern)
    {
      const bf16* ag = A + (size_t)(row0 + wv*16 + srow)*STR + k0 + schk*8;
      gload_lds16(ag,            As + wv*512 + lane*8);
      gload_lds16(ag + 64*STR,   As + 2048 + wv*512 + lane*8);
      const bf16* bg = Wt + (size_t)(n0 + wv*16 + srow)*STR + k0 + schk*8;
      gload_lds16(bg,            Bs + wv*512 + lane*8);
      gload_lds16(bg + 64*STR,   Bs + 2048 + wv*512 + lane*8);
    }
    __syncthreads();
    frag8 a[4], b[4];
    #pragma unroll
    for (int mi=0;mi<4;++mi)
      a[mi] = *(const frag8*)(As + (wm*64 + mi*16 + fr)*32 + fq*8);
    #pragma unroll
    for (int ni=0;ni<4;++ni)
      b[ni] = *(const frag8*)(Bs + (wn*64 + ni*16 + fr)*32 + fq*8);
    #pragma unroll
    for (int mi=0;mi<4;++mi)
      #pragma unroll
      for (int ni=0;ni<4;++ni)
        acc[mi][ni] = __builtin_amdgcn_mfma_f32_16x16x32_bf16(a[mi], b[ni], acc[mi][ni], 0, 0, 0);
    __syncthreads();
  }

  // epilogue: C/D layout col=lane&15, row=(lane>>4)*4+reg  [m89/m91-verified]
  #pragma unroll
  for (int mi=0;mi<4;++mi){
    int row = row0 + wm*64 + mi*16 + fq*4;
    #pragma unroll
    for (int ni=0;ni<4;++ni){
      int col = n0 + wn*64 + ni*16 + fr;
      if (col < EMB){
        bf16* cp = C + (size_t)row*STR + col;
        #pragma unroll
        for (int r=0;r<4;++r)
          cp[(size_t)r*STR] = __float2bfloat16(sigmoidf_(acc[mi][ni][r]));
      }
    }
  }
}

// ---------------- FC1: h1 = sigmoid([H2[node], input] @ Wa + ba) ----------------

__global__ __launch_bounds__(256) void k_fc1(const bf16* __restrict__ H2,
                                             const int* __restrict__ node,
                                             const float* __restrict__ input,
                                             const float* __restrict__ Wa,
                                             const float* __restrict__ ba,
                                             float* __restrict__ h1){
  __shared__ float As[16][64];
  __shared__ float Ws[16][64];
  __shared__ int snode[64];
  int tid = threadIdx.x;
  int tx = tid & 15, ty = tid >> 4;
  int row0 = blockIdx.x*64, n0 = blockIdx.y*64;
  if (tid < 64) snode[tid] = node[row0 + tid];
  __syncthreads();
  float acc[4][4] = {};
  int lr = tid >> 2, lq = (tid & 3) * 4;
  int wk = tid >> 4, wc = (tid & 15) * 4;
  const int K = EMB + IN_DIM;  // 1068
  for (int k0 = 0; k0 < K; k0 += 16){
    int r = row0 + lr;
    const bf16* hrow = H2 + (size_t)snode[lr]*STR;
    #pragma unroll
    for (int i=0;i<4;++i){
      int k = k0 + lq + i;
      float v = 0.0f;
      if (k < EMB) v = __bfloat162float(hrow[k]);
      else if (k < K) v = input[(size_t)r*IN_DIM + (k - EMB)];
      As[lq+i][lr] = v;
    }
    int kk = k0 + wk;
    #pragma unroll
    for (int i=0;i<4;++i){
      int col = n0 + wc + i;
      Ws[wk][wc+i] = (kk < K && col < HID) ? Wa[(size_t)kk*HID + col] : 0.0f;
    }
    __syncthreads();
    #pragma unroll
    for (int p=0;p<16;++p){
      float ra[4], rb[4];
      #pragma unroll
      for (int i=0;i<4;++i) ra[i] = As[p][ty*4+i];
      #pragma unroll
      for (int j=0;j<4;++j) rb[j] = Ws[p][tx*4+j];
      #pragma unroll
      for (int i=0;i<4;++i)
        #pragma unroll
        for (int j=0;j<4;++j) acc[i][j] += ra[i]*rb[j];
    }
    __syncthreads();
  }
  #pragma unroll
  for (int i=0;i<4;++i){
    int row = row0 + ty*4 + i;
    #pragma unroll
    for (int j=0;j<4;++j){
      int col = n0 + tx*4 + j;
      if (col < HID) h1[(size_t)row*HID + col] = sigmoidf_(acc[i][j] + ba[col]);
    }
  }
}

// ---------------- FC2: h2 = sigmoid(h1 @ Wb + bb) ----------------

__global__ __launch_bounds__(256) void k_fc2(const float* __restrict__ h1,
                                             const float* __restrict__ Wb,
                                             const float* __restrict__ bb,
                                             float* __restrict__ h2){
  __shared__ float As[16][64];
  __shared__ float Ws[16][64];
  int tid = threadIdx.x;
  int tx = tid & 15, ty = tid >> 4;
  int row0 = blockIdx.x*64, n0 = blockIdx.y*64;
  float acc[4][4] = {};
  int lr = tid >> 2, lq = (tid & 3) * 4;
  int wk = tid >> 4, wc = (tid & 15) * 4;
  for (int k0 = 0; k0 < HID; k0 += 16){
    int r = row0 + lr;
    #pragma unroll
    for (int i=0;i<4;++i){
      int k = k0 + lq + i;
      As[lq+i][lr] = (k < HID) ? h1[(size_t)r*HID + k] : 0.0f;
    }
    int kk = k0 + wk;
    #pragma unroll
    for (int i=0;i<4;++i){
      int col = n0 + wc + i;
      Ws[wk][wc+i] = (kk < HID && col < HID) ? Wb[(size_t)kk*HID + col] : 0.0f;
    }
    __syncthreads();
    #pragma unroll
    for (int p=0;p<16;++p){
      float ra[4], rb[4];
      #pragma unroll
      for (int i=0;i<4;++i) ra[i] = As[p][ty*4+i];
      #pragma unroll
      for (int j=0;j<4;++j) rb[j] = Ws[p][tx*4+j];
      #pragma unroll
      for (int i=0;i<4;++i)
        #pragma unroll
        for (int j=0;j<4;++j) acc[i][j] += ra[i]*rb[j];
    }
    __syncthreads();
  }
  #pragma unroll
  for (int i=0;i<4;++i){
    int row = row0 + ty*4 + i;
    #pragma unroll
    for (int j=0;j<4;++j){
      int col = n0 + tx*4 + j;
      if (col < HID) h2[(size_t)row*HID + col] = sigmoidf_(acc[i][j] + bb[col]);
    }
  }
}

// ---------------- FC3: out = h2 @ Wc + bc  (wave per batch row) ----------------

__global__ __launch_bounds__(256) void k_fc3(const float* __restrict__ h2,
                                             const float* __restrict__ Wc,
                                             const float* __restrict__ bc,
                                             float* __restrict__ out){
  int w = (int)((blockIdx.x*blockDim.x + threadIdx.x) >> 6);
  int lane = threadIdx.x & 63;
  if (w >= BATCH) return;
  const float* hr = h2 + (size_t)w*HID;
  float a0 = 0.f, a1 = 0.f;
  for (int k = lane; k < HID; k += 64){
    float h = hr[k];
    a0 += h * Wc[k*2+0];
    a1 += h * Wc[k*2+1];
  }
  #pragma unroll
  for (int off = 32; off; off >>= 1){
    a0 += __shfl_down(a0, off);
    a1 += __shfl_down(a1, off);
  }
  if (lane == 0){
    out[w*2+0] = a0 + bc[0];
    out[w*2+1] = a1 + bc[1];
  }
}

// ---------------- launch ----------------

extern "C" void kernel_launch(void* const* d_in, const int* in_sizes, int n_in,
                              void* d_out, int out_size, void* d_ws, size_t ws_size,
                              hipStream_t stream){
  const float* input = (const float*)d_in[0];
  const int*   node  = (const int*)d_in[1];
  const int*   erow  = (const int*)d_in[2];
  const int*   ecol  = (const int*)d_in[3];
  const float* H0    = (const float*)d_in[4];
  const float* W1    = (const float*)d_in[5];
  const float* W2    = (const float*)d_in[6];
  const float* Wa    = (const float*)d_in[7];
  const float* ba    = (const float*)d_in[8];
  const float* Wb    = (const float*)d_in[9];
  const float* bb    = (const float*)d_in[10];
  const float* Wc    = (const float*)d_in[11];
  const float* bc    = (const float*)d_in[12];

  char* p = (char*)d_ws;
  auto alloc = [&](size_t bytes)->char*{ char* r = p; p += (bytes + 255) & ~(size_t)255; return r; };
  int*   deg    = (int*)  alloc((size_t)NVX*4);
  float* dinv   = (float*)alloc((size_t)NVX*4);
  int*   rowptr = (int*)  alloc((size_t)(NVX+1)*4);
  int*   cursor = (int*)  alloc((size_t)NVX*4);
  int*   ccol   = (int*)  alloc((size_t)NEX*4);
  float* cval   = (float*)alloc((size_t)NEX*4);
  bf16*  G      = (bf16*) alloc((size_t)NVR*STR*2);
  bf16*  Hb     = (bf16*) alloc((size_t)NVR*STR*2);
  bf16*  Wt     = (bf16*) alloc((size_t)NPAD*STR*2);
  float* h1     = (float*)alloc((size_t)BATCH*HID*4);
  float* h2     = (float*)alloc((size_t)BATCH*HID*4);

  hipMemsetAsync(deg, 0, (size_t)NVX*4, stream);
  k_deg    <<<(NEX+255)/256, 256, 0, stream>>>(erow, deg);
  k_dinv   <<<(NVX+255)/256, 256, 0, stream>>>(deg, dinv);
  k_scan   <<<1, 1024, 0, stream>>>(deg, rowptr, cursor);
  k_scatter<<<(NEX+255)/256, 256, 0, stream>>>(erow, ecol, dinv, cursor, ccol, cval);

  dim3 ggrid(NPAD/128, NVR/128);

  // G1 = LM @ H0 ; H1 = sigmoid(G1 @ W1)   (associativity: LM@(H0@W1) == (LM@H0)@W1)
  k_prepW<<<(NPAD*STR+255)/256, 256, 0, stream>>>(W1, Wt);
  k_spmm<float><<<NVR/4, 256, 0, stream>>>(rowptr, ccol, cval, H0, EMB, G);
  k_gemm_mfma<<<ggrid, 256, 0, stream>>>(G, Wt, Hb);
  // G2 = LM @ H1 ; H2 = sigmoid(G2 @ W2)
  k_prepW<<<(NPAD*STR+255)/256, 256, 0, stream>>>(W2, Wt);
  k_spmm<bf16> <<<NVR/4, 256, 0, stream>>>(rowptr, ccol, cval, Hb, STR, G);
  k_gemm_mfma<<<ggrid, 256, 0, stream>>>(G, Wt, Hb);

  k_fc1<<<dim3(BATCH/64, (HID+63)/64), 256, 0, stream>>>(Hb, node, input, Wa, ba, h1);
  k_fc2<<<dim3(BATCH/64, (HID+63)/64), 256, 0, stream>>>(h1, Wb, bb, h2);
  k_fc3<<<BATCH/4, 256, 0, stream>>>(h2, Wc, bc, (float*)d_out);
}

// Round 3
// 855.357 us; speedup vs baseline: 1.8954x; 1.2929x over previous
//
#include <hip/hip_runtime.h>
#include <hip/hip_bf16.h>

typedef __hip_bfloat16 bf16;

#define NVX 117000
#define NVR 117120         // rows padded to multiple of 128 (= 915*128)
#define NEX 468000
#define EMB 300
#define STR 320            // padded K/row stride for bf16 node buffers (pads zeroed)
#define NPAD 384           // padded N for node GEMM (3 tiles of 128)
#define IN_DIM 768
#define BATCH 4096
#define HID 500
#define NB 458             // scan blocks: ceil(NVX/256)

typedef __attribute__((ext_vector_type(8))) short frag8;   // 8 bf16 (4 VGPRs)
typedef __attribute__((ext_vector_type(4))) float f32x4;   // 4 fp32 acc

__device__ __forceinline__ float sigmoidf_(float x){ return 1.0f/(1.0f + __expf(-x)); }
__device__ __forceinline__ float ldf(const float* p){ return *p; }
__device__ __forceinline__ float ldf(const bf16* p){ return __bfloat162float(*p); }

__device__ __forceinline__ void gload_lds16(const bf16* g, bf16* l){
  __builtin_amdgcn_global_load_lds((const __attribute__((address_space(1))) void*)g,
                                   (__attribute__((address_space(3))) void*)l, 16, 0, 0);
}

// ---------------- graph preprocessing ----------------

__global__ void k_deg(const int* __restrict__ erow, int* __restrict__ deg){
  int i = blockIdx.x*blockDim.x + threadIdx.x;
  if (i < NEX) atomicAdd(&deg[erow[i]], 1);
}

__global__ void k_dinv(const int* __restrict__ deg, float* __restrict__ dinv){
  int i = blockIdx.x*blockDim.x + threadIdx.x;
  if (i < NVX){ int d = deg[i]; dinv[i] = d > 0 ? rsqrtf((float)d) : 0.0f; }
}

// hierarchical exclusive scan of deg -> rowptr (+cursor copy)
__global__ __launch_bounds__(256) void k_partsum(const int* __restrict__ deg,
                                                 int* __restrict__ bsum){
  __shared__ int s[256];
  int t = threadIdx.x;
  int i = blockIdx.x*256 + t;
  s[t] = (i < NVX) ? deg[i] : 0;
  __syncthreads();
  #pragma unroll
  for (int off=128; off; off>>=1){
    if (t < off) s[t] += s[t+off];
    __syncthreads();
  }
  if (t == 0) bsum[blockIdx.x] = s[0];
}

__global__ __launch_bounds__(512) void k_scanb(const int* __restrict__ bsum,
                                               int* __restrict__ boff,
                                               int* __restrict__ rowptr){
  __shared__ int s[512];
  int t = threadIdx.x;
  int v = (t < NB) ? bsum[t] : 0;
  s[t] = v; __syncthreads();
  #pragma unroll
  for (int off=1; off<512; off<<=1){
    int u = (t>=off) ? s[t-off] : 0;
    __syncthreads();
    s[t] += u;
    __syncthreads();
  }
  if (t < NB) boff[t] = s[t] - v;        // exclusive block offsets
  if (t == 511) rowptr[NVX] = s[511];    // total
}

__global__ __launch_bounds__(256) void k_writeptr(const int* __restrict__ deg,
                                                  const int* __restrict__ boff,
                                                  int* __restrict__ rowptr,
                                                  int* __restrict__ cursor){
  __shared__ int s[256];
  int t = threadIdx.x;
  int i = blockIdx.x*256 + t;
  int v = (i < NVX) ? deg[i] : 0;
  s[t] = v; __syncthreads();
  #pragma unroll
  for (int off=1; off<256; off<<=1){
    int u = (t>=off) ? s[t-off] : 0;
    __syncthreads();
    s[t] += u;
    __syncthreads();
  }
  if (i < NVX){
    int e = boff[blockIdx.x] + s[t] - v;  // exclusive prefix
    rowptr[i] = e;
    cursor[i] = e;
  }
}

__global__ void k_scatter(const int* __restrict__ erow, const int* __restrict__ ecol,
                          const float* __restrict__ dinv, int* __restrict__ cursor,
                          int* __restrict__ ccol, float* __restrict__ cval){
  int i = blockIdx.x*blockDim.x + threadIdx.x;
  if (i < NEX){
    int r = erow[i], c = ecol[i];
    int p = atomicAdd(&cursor[r], 1);
    ccol[p] = c;
    cval[p] = dinv[r]*dinv[c];
  }
}

// W (f32, [300,300] k-major) -> Wt (bf16, [NPAD][STR] n-major, zero-padded)
__global__ void k_prepW(const float* __restrict__ W, bf16* __restrict__ Wt){
  int i = blockIdx.x*blockDim.x + threadIdx.x;
  if (i >= NPAD*STR) return;
  int n = i / STR, k = i % STR;
  float v = (n < EMB && k < EMB) ? W[k*EMB + n] : 0.0f;
  Wt[i] = __float2bfloat16(v);
}

// ---------------- spmm: Y[v,:] = sum_e val * X[col(e),:]  (wave per row) ----------------

template<typename T>
__global__ __launch_bounds__(256) void k_spmm(const int* __restrict__ rowptr,
                                              const int* __restrict__ ccol,
                                              const float* __restrict__ cval,
                                              const T* __restrict__ X, int xstride,
                                              bf16* __restrict__ Y){
  int w = (int)((blockIdx.x*blockDim.x + threadIdx.x) >> 6);
  int lane = threadIdx.x & 63;
  if (w >= NVR) return;
  bf16* yr = Y + (size_t)w*STR;
  if (w >= NVX){   // pad rows: keep zero so MFMA A-tiles read clean data
    #pragma unroll
    for (int j=0;j<5;++j) yr[lane + 64*j] = __float2bfloat16(0.0f);
    return;
  }
  float acc[5] = {0.f,0.f,0.f,0.f,0.f};
  int e0 = rowptr[w], e1 = rowptr[w+1];
  for (int e=e0; e<e1; ++e){
    float v = cval[e];
    const T* xr = X + (size_t)ccol[e]*xstride;
    #pragma unroll
    for (int j=0;j<5;++j){
      int col = lane + 64*j;
      if (col < EMB) acc[j] += v * ldf(xr + col);
    }
  }
  #pragma unroll
  for (int j=0;j<5;++j){
    int col = lane + 64*j;
    yr[col] = __float2bfloat16(col < EMB ? acc[j] : 0.0f);
  }
}

// ---------------- node GEMM (MFMA): C = sigmoid(A @ W), A bf16 [NVR,STR], Wt bf16 [NPAD][STR] ----------------

__global__ __launch_bounds__(256) void k_gemm_mfma(const bf16* __restrict__ A,
                                                   const bf16* __restrict__ Wt,
                                                   bf16* __restrict__ C){
  __shared__ bf16 As[128*32];
  __shared__ bf16 Bs[128*32];
  const int tid  = threadIdx.x;
  const int wv   = tid >> 6;
  const int lane = tid & 63;
  const int row0 = blockIdx.y * 128;
  const int n0   = blockIdx.x * 128;
  const int wm = wv & 1, wn = wv >> 1;

  f32x4 acc[4][4];
  #pragma unroll
  for (int i=0;i<4;++i)
    #pragma unroll
    for (int j=0;j<4;++j) acc[i][j] = (f32x4)(0.0f);

  const int srow = lane >> 2;     // 0..15 staging row within wave stripe
  const int schk = lane & 3;      // 16B chunk within 64B (=32 bf16) row

  const int fr = lane & 15;       // fragment row/col index
  const int fq = lane >> 4;       // quad -> k offset = fq*8

  for (int k0 = 0; k0 < STR; k0 += 32){
    {
      const bf16* ag = A + (size_t)(row0 + wv*16 + srow)*STR + k0 + schk*8;
      gload_lds16(ag,            As + wv*512 + lane*8);
      gload_lds16(ag + 64*STR,   As + 2048 + wv*512 + lane*8);
      const bf16* bg = Wt + (size_t)(n0 + wv*16 + srow)*STR + k0 + schk*8;
      gload_lds16(bg,            Bs + wv*512 + lane*8);
      gload_lds16(bg + 64*STR,   Bs + 2048 + wv*512 + lane*8);
    }
    __syncthreads();
    frag8 a[4], b[4];
    #pragma unroll
    for (int mi=0;mi<4;++mi)
      a[mi] = *(const frag8*)(As + (wm*64 + mi*16 + fr)*32 + fq*8);
    #pragma unroll
    for (int ni=0;ni<4;++ni)
      b[ni] = *(const frag8*)(Bs + (wn*64 + ni*16 + fr)*32 + fq*8);
    #pragma unroll
    for (int mi=0;mi<4;++mi)
      #pragma unroll
      for (int ni=0;ni<4;++ni)
        acc[mi][ni] = __builtin_amdgcn_mfma_f32_16x16x32_bf16(a[mi], b[ni], acc[mi][ni], 0, 0, 0);
    __syncthreads();
  }

  // epilogue: C/D layout col=lane&15, row=(lane>>4)*4+reg  [m89/m91-verified]
  #pragma unroll
  for (int mi=0;mi<4;++mi){
    int row = row0 + wm*64 + mi*16 + fq*4;
    #pragma unroll
    for (int ni=0;ni<4;++ni){
      int col = n0 + wn*64 + ni*16 + fr;
      if (col < EMB){
        bf16* cp = C + (size_t)row*STR + col;
        #pragma unroll
        for (int r=0;r<4;++r)
          cp[(size_t)r*STR] = __float2bfloat16(sigmoidf_(acc[mi][ni][r]));
      }
    }
  }
}

// ---------------- FC1: h1 = sigmoid([H2[node], input] @ Wa + ba) ----------------

__global__ __launch_bounds__(256) void k_fc1(const bf16* __restrict__ H2,
                                             const int* __restrict__ node,
                                             const float* __restrict__ input,
                                             const float* __restrict__ Wa,
                                             const float* __restrict__ ba,
                                             float* __restrict__ h1){
  __shared__ float As[16][64];
  __shared__ float Ws[16][64];
  __shared__ int snode[64];
  int tid = threadIdx.x;
  int tx = tid & 15, ty = tid >> 4;
  int row0 = blockIdx.x*64, n0 = blockIdx.y*64;
  if (tid < 64) snode[tid] = node[row0 + tid];
  __syncthreads();
  float acc[4][4] = {};
  int lr = tid >> 2, lq = (tid & 3) * 4;
  int wk = tid >> 4, wc = (tid & 15) * 4;
  const int K = EMB + IN_DIM;  // 1068
  for (int k0 = 0; k0 < K; k0 += 16){
    int r = row0 + lr;
    const bf16* hrow = H2 + (size_t)snode[lr]*STR;
    #pragma unroll
    for (int i=0;i<4;++i){
      int k = k0 + lq + i;
      float v = 0.0f;
      if (k < EMB) v = __bfloat162float(hrow[k]);
      else if (k < K) v = input[(size_t)r*IN_DIM + (k - EMB)];
      As[lq+i][lr] = v;
    }
    int kk = k0 + wk;
    #pragma unroll
    for (int i=0;i<4;++i){
      int col = n0 + wc + i;
      Ws[wk][wc+i] = (kk < K && col < HID) ? Wa[(size_t)kk*HID + col] : 0.0f;
    }
    __syncthreads();
    #pragma unroll
    for (int p=0;p<16;++p){
      float ra[4], rb[4];
      #pragma unroll
      for (int i=0;i<4;++i) ra[i] = As[p][ty*4+i];
      #pragma unroll
      for (int j=0;j<4;++j) rb[j] = Ws[p][tx*4+j];
      #pragma unroll
      for (int i=0;i<4;++i)
        #pragma unroll
        for (int j=0;j<4;++j) acc[i][j] += ra[i]*rb[j];
    }
    __syncthreads();
  }
  #pragma unroll
  for (int i=0;i<4;++i){
    int row = row0 + ty*4 + i;
    #pragma unroll
    for (int j=0;j<4;++j){
      int col = n0 + tx*4 + j;
      if (col < HID) h1[(size_t)row*HID + col] = sigmoidf_(acc[i][j] + ba[col]);
    }
  }
}

// ---------------- FC2: h2 = sigmoid(h1 @ Wb + bb) ----------------

__global__ __launch_bounds__(256) void k_fc2(const float* __restrict__ h1,
                                             const float* __restrict__ Wb,
                                             const float* __restrict__ bb,
                                             float* __restrict__ h2){
  __shared__ float As[16][64];
  __shared__ float Ws[16][64];
  int tid = threadIdx.x;
  int tx = tid & 15, ty = tid >> 4;
  int row0 = blockIdx.x*64, n0 = blockIdx.y*64;
  float acc[4][4] = {};
  int lr = tid >> 2, lq = (tid & 3) * 4;
  int wk = tid >> 4, wc = (tid & 15) * 4;
  for (int k0 = 0; k0 < HID; k0 += 16){
    int r = row0 + lr;
    #pragma unroll
    for (int i=0;i<4;++i){
      int k = k0 + lq + i;
      As[lq+i][lr] = (k < HID) ? h1[(size_t)r*HID + k] : 0.0f;
    }
    int kk = k0 + wk;
    #pragma unroll
    for (int i=0;i<4;++i){
      int col = n0 + wc + i;
      Ws[wk][wc+i] = (kk < HID && col < HID) ? Wb[(size_t)kk*HID + col] : 0.0f;
    }
    __syncthreads();
    #pragma unroll
    for (int p=0;p<16;++p){
      float ra[4], rb[4];
      #pragma unroll
      for (int i=0;i<4;++i) ra[i] = As[p][ty*4+i];
      #pragma unroll
      for (int j=0;j<4;++j) rb[j] = Ws[p][tx*4+j];
      #pragma unroll
      for (int i=0;i<4;++i)
        #pragma unroll
        for (int j=0;j<4;++j) acc[i][j] += ra[i]*rb[j];
    }
    __syncthreads();
  }
  #pragma unroll
  for (int i=0;i<4;++i){
    int row = row0 + ty*4 + i;
    #pragma unroll
    for (int j=0;j<4;++j){
      int col = n0 + tx*4 + j;
      if (col < HID) h2[(size_t)row*HID + col] = sigmoidf_(acc[i][j] + bb[col]);
    }
  }
}

// ---------------- FC3: out = h2 @ Wc + bc  (wave per batch row) ----------------

__global__ __launch_bounds__(256) void k_fc3(const float* __restrict__ h2,
                                             const float* __restrict__ Wc,
                                             const float* __restrict__ bc,
                                             float* __restrict__ out){
  int w = (int)((blockIdx.x*blockDim.x + threadIdx.x) >> 6);
  int lane = threadIdx.x & 63;
  if (w >= BATCH) return;
  const float* hr = h2 + (size_t)w*HID;
  float a0 = 0.f, a1 = 0.f;
  for (int k = lane; k < HID; k += 64){
    float h = hr[k];
    a0 += h * Wc[k*2+0];
    a1 += h * Wc[k*2+1];
  }
  #pragma unroll
  for (int off = 32; off; off >>= 1){
    a0 += __shfl_down(a0, off);
    a1 += __shfl_down(a1, off);
  }
  if (lane == 0){
    out[w*2+0] = a0 + bc[0];
    out[w*2+1] = a1 + bc[1];
  }
}

// ---------------- launch ----------------

extern "C" void kernel_launch(void* const* d_in, const int* in_sizes, int n_in,
                              void* d_out, int out_size, void* d_ws, size_t ws_size,
                              hipStream_t stream){
  const float* input = (const float*)d_in[0];
  const int*   node  = (const int*)d_in[1];
  const int*   erow  = (const int*)d_in[2];
  const int*   ecol  = (const int*)d_in[3];
  const float* H0    = (const float*)d_in[4];
  const float* W1    = (const float*)d_in[5];
  const float* W2    = (const float*)d_in[6];
  const float* Wa    = (const float*)d_in[7];
  const float* ba    = (const float*)d_in[8];
  const float* Wb    = (const float*)d_in[9];
  const float* bb    = (const float*)d_in[10];
  const float* Wc    = (const float*)d_in[11];
  const float* bc    = (const float*)d_in[12];

  char* p = (char*)d_ws;
  auto alloc = [&](size_t bytes)->char*{ char* r = p; p += (bytes + 255) & ~(size_t)255; return r; };
  int*   deg    = (int*)  alloc((size_t)NVX*4);
  float* dinv   = (float*)alloc((size_t)NVX*4);
  int*   rowptr = (int*)  alloc((size_t)(NVX+1)*4);
  int*   cursor = (int*)  alloc((size_t)NVX*4);
  int*   bsum   = (int*)  alloc((size_t)NB*4);
  int*   boff   = (int*)  alloc((size_t)NB*4);
  int*   ccol   = (int*)  alloc((size_t)NEX*4);
  float* cval   = (float*)alloc((size_t)NEX*4);
  bf16*  G      = (bf16*) alloc((size_t)NVR*STR*2);
  bf16*  Hb     = (bf16*) alloc((size_t)NVR*STR*2);
  bf16*  Wt     = (bf16*) alloc((size_t)NPAD*STR*2);
  float* h1     = (float*)alloc((size_t)BATCH*HID*4);
  float* h2     = (float*)alloc((size_t)BATCH*HID*4);

  hipMemsetAsync(deg, 0, (size_t)NVX*4, stream);
  k_deg     <<<(NEX+255)/256, 256, 0, stream>>>(erow, deg);
  k_dinv    <<<(NVX+255)/256, 256, 0, stream>>>(deg, dinv);
  k_partsum <<<NB, 256, 0, stream>>>(deg, bsum);
  k_scanb   <<<1, 512, 0, stream>>>(bsum, boff, rowptr);
  k_writeptr<<<NB, 256, 0, stream>>>(deg, boff, rowptr, cursor);
  k_scatter <<<(NEX+255)/256, 256, 0, stream>>>(erow, ecol, dinv, cursor, ccol, cval);

  dim3 ggrid(NPAD/128, NVR/128);

  // G1 = LM @ H0 ; H1 = sigmoid(G1 @ W1)   (associativity: LM@(H0@W1) == (LM@H0)@W1)
  k_prepW<<<(NPAD*STR+255)/256, 256, 0, stream>>>(W1, Wt);
  k_spmm<float><<<NVR/4, 256, 0, stream>>>(rowptr, ccol, cval, H0, EMB, G);
  k_gemm_mfma<<<ggrid, 256, 0, stream>>>(G, Wt, Hb);
  // G2 = LM @ H1 ; H2 = sigmoid(G2 @ W2)
  k_prepW<<<(NPAD*STR+255)/256, 256, 0, stream>>>(W2, Wt);
  k_spmm<bf16> <<<NVR/4, 256, 0, stream>>>(rowptr, ccol, cval, Hb, STR, G);
  k_gemm_mfma<<<ggrid, 256, 0, stream>>>(G, Wt, Hb);

  k_fc1<<<dim3(BATCH/64, (HID+63)/64), 256, 0, stream>>>(Hb, node, input, Wa, ba, h1);
  k_fc2<<<dim3(BATCH/64, (HID+63)/64), 256, 0, stream>>>(h1, Wb, bb, h2);
  k_fc3<<<BATCH/4, 256, 0, stream>>>(h2, Wc, bc, (float*)d_out);
}

// Round 4
// 680.757 us; speedup vs baseline: 2.3816x; 1.2565x over previous
//
#include <hip/hip_runtime.h>
#include <hip/hip_bf16.h>

typedef __hip_bfloat16 bf16;

#define NVX 117000
#define NVR 117120         // rows padded to multiple of 128 (= 915*128)
#define NEX 468000
#define EMB 300
#define STR 320            // padded K/row stride for bf16 node buffers (pads zeroed)
#define NPAD 384           // padded N for node GEMM (3 tiles of 128)
#define IN_DIM 768
#define BATCH 4096
#define HID 500
#define FCK 1088           // FC1 K padded (300+768=1068 -> 34*32)
#define HPAD 512           // FC hidden padded
#define NB 458             // scan blocks: ceil(NVX/256)

typedef __attribute__((ext_vector_type(8))) short frag8;   // 8 bf16 (4 VGPRs)
typedef __attribute__((ext_vector_type(4))) float f32x4;   // 4 fp32 acc

__device__ __forceinline__ float sigmoidf_(float x){ return 1.0f/(1.0f + __expf(-x)); }
__device__ __forceinline__ float ldf(const float* p){ return *p; }
__device__ __forceinline__ float ldf(const bf16* p){ return __bfloat162float(*p); }

__device__ __forceinline__ void gload_lds16(const bf16* g, bf16* l){
  __builtin_amdgcn_global_load_lds((const __attribute__((address_space(1))) void*)g,
                                   (__attribute__((address_space(3))) void*)l, 16, 0, 0);
}

// ---------------- graph preprocessing ----------------

__global__ void k_deg(const int* __restrict__ erow, int* __restrict__ deg){
  int i = blockIdx.x*blockDim.x + threadIdx.x;
  if (i < NEX) atomicAdd(&deg[erow[i]], 1);
}

__global__ void k_dinv(const int* __restrict__ deg, float* __restrict__ dinv){
  int i = blockIdx.x*blockDim.x + threadIdx.x;
  if (i < NVX){ int d = deg[i]; dinv[i] = d > 0 ? rsqrtf((float)d) : 0.0f; }
}

// hierarchical exclusive scan of deg -> rowptr (+cursor copy)
__global__ __launch_bounds__(256) void k_partsum(const int* __restrict__ deg,
                                                 int* __restrict__ bsum){
  __shared__ int s[256];
  int t = threadIdx.x;
  int i = blockIdx.x*256 + t;
  s[t] = (i < NVX) ? deg[i] : 0;
  __syncthreads();
  #pragma unroll
  for (int off=128; off; off>>=1){
    if (t < off) s[t] += s[t+off];
    __syncthreads();
  }
  if (t == 0) bsum[blockIdx.x] = s[0];
}

__global__ __launch_bounds__(512) void k_scanb(const int* __restrict__ bsum,
                                               int* __restrict__ boff,
                                               int* __restrict__ rowptr){
  __shared__ int s[512];
  int t = threadIdx.x;
  int v = (t < NB) ? bsum[t] : 0;
  s[t] = v; __syncthreads();
  #pragma unroll
  for (int off=1; off<512; off<<=1){
    int u = (t>=off) ? s[t-off] : 0;
    __syncthreads();
    s[t] += u;
    __syncthreads();
  }
  if (t < NB) boff[t] = s[t] - v;        // exclusive block offsets
  if (t == 511) rowptr[NVX] = s[511];    // total
}

__global__ __launch_bounds__(256) void k_writeptr(const int* __restrict__ deg,
                                                  const int* __restrict__ boff,
                                                  int* __restrict__ rowptr,
                                                  int* __restrict__ cursor){
  __shared__ int s[256];
  int t = threadIdx.x;
  int i = blockIdx.x*256 + t;
  int v = (i < NVX) ? deg[i] : 0;
  s[t] = v; __syncthreads();
  #pragma unroll
  for (int off=1; off<256; off<<=1){
    int u = (t>=off) ? s[t-off] : 0;
    __syncthreads();
    s[t] += u;
    __syncthreads();
  }
  if (i < NVX){
    int e = boff[blockIdx.x] + s[t] - v;  // exclusive prefix
    rowptr[i] = e;
    cursor[i] = e;
  }
}

__global__ void k_scatter(const int* __restrict__ erow, const int* __restrict__ ecol,
                          const float* __restrict__ dinv, int* __restrict__ cursor,
                          int* __restrict__ ccol, float* __restrict__ cval){
  int i = blockIdx.x*blockDim.x + threadIdx.x;
  if (i < NEX){
    int r = erow[i], c = ecol[i];
    int p = atomicAdd(&cursor[r], 1);
    ccol[p] = c;
    cval[p] = dinv[r]*dinv[c];
  }
}

// W (f32, [kdim, ndim] k-major) -> Wt (bf16, [npad][kpad] n-major, zero-padded)
__global__ void k_prepW(const float* __restrict__ W, bf16* __restrict__ Wt,
                        int kdim, int ndim, int kpad, int npad){
  int i = blockIdx.x*blockDim.x + threadIdx.x;
  if (i >= npad*kpad) return;
  int n = i / kpad, k = i % kpad;
  float v = (n < ndim && k < kdim) ? W[k*ndim + n] : 0.0f;
  Wt[i] = __float2bfloat16(v);
}

// Afc[r][k] = H2[node[r]][k] (k<300) | input[r][k-300] (k<1068) | 0
__global__ __launch_bounds__(256) void k_prepA(const bf16* __restrict__ H2,
                                               const int* __restrict__ node,
                                               const float* __restrict__ input,
                                               bf16* __restrict__ Afc){
  int k = blockIdx.x*256 + threadIdx.x;
  int r = blockIdx.y;
  if (k >= FCK) return;
  bf16 v;
  if (k < EMB)           v = H2[(size_t)node[r]*STR + k];
  else if (k < EMB+IN_DIM) v = __float2bfloat16(input[(size_t)r*IN_DIM + (k - EMB)]);
  else                   v = __float2bfloat16(0.0f);
  Afc[(size_t)r*FCK + k] = v;
}

// ---------------- spmm: Y[v,:] = sum_e val * X[col(e),:]  (wave per row) ----------------

template<typename T>
__global__ __launch_bounds__(256) void k_spmm(const int* __restrict__ rowptr,
                                              const int* __restrict__ ccol,
                                              const float* __restrict__ cval,
                                              const T* __restrict__ X, int xstride,
                                              bf16* __restrict__ Y){
  int w = (int)((blockIdx.x*blockDim.x + threadIdx.x) >> 6);
  int lane = threadIdx.x & 63;
  if (w >= NVR) return;
  bf16* yr = Y + (size_t)w*STR;
  if (w >= NVX){   // pad rows: keep zero so MFMA A-tiles read clean data
    #pragma unroll
    for (int j=0;j<5;++j) yr[lane + 64*j] = __float2bfloat16(0.0f);
    return;
  }
  float acc[5] = {0.f,0.f,0.f,0.f,0.f};
  int e0 = rowptr[w], e1 = rowptr[w+1];
  for (int e=e0; e<e1; ++e){
    float v = cval[e];
    const T* xr = X + (size_t)ccol[e]*xstride;
    #pragma unroll
    for (int j=0;j<5;++j){
      int col = lane + 64*j;
      if (col < EMB) acc[j] += v * ldf(xr + col);
    }
  }
  #pragma unroll
  for (int j=0;j<5;++j){
    int col = lane + 64*j;
    yr[col] = __float2bfloat16(col < EMB ? acc[j] : 0.0f);
  }
}

// ---------------- generic 128x128 MFMA GEMM, compile-time K, epilogue select ----------------
// grid = (Ncols/128, Mrows/128). A [M][KS] bf16, B [N][KS] bf16 (n-major).
// EPI 0: node gemm  -> Cb bf16 stride STR, sigmoid, cols < EMB only
// EPI 1: FC1        -> Cb bf16 stride HPAD, sigmoid(acc + bias[col<HID?]), all cols
// EPI 2: FC2        -> Cf f32  stride HID, sigmoid(acc + bias), cols < HID only

template<int KS, int EPI>
__global__ __launch_bounds__(256) void k_mfma_gemm(const bf16* __restrict__ A,
                                                   const bf16* __restrict__ B,
                                                   bf16* __restrict__ Cb,
                                                   float* __restrict__ Cf,
                                                   const float* __restrict__ bias){
  __shared__ bf16 As[128*32];
  __shared__ bf16 Bs[128*32];
  const int tid  = threadIdx.x;
  const int wv   = tid >> 6;
  const int lane = tid & 63;
  const int row0 = blockIdx.y * 128;
  const int n0   = blockIdx.x * 128;
  const int wm = wv & 1, wn = wv >> 1;

  f32x4 acc[4][4];
  #pragma unroll
  for (int i=0;i<4;++i)
    #pragma unroll
    for (int j=0;j<4;++j) acc[i][j] = (f32x4)(0.0f);

  const int srow = lane >> 2;     // 0..15 staging row within wave stripe
  const int schk = lane & 3;      // 16B chunk within 64B (=32 bf16) row
  const int fr = lane & 15;       // fragment row/col index
  const int fq = lane >> 4;       // quad -> k offset = fq*8

  for (int k0 = 0; k0 < KS; k0 += 32){
    {
      const bf16* ag = A + (size_t)(row0 + wv*16 + srow)*KS + k0 + schk*8;
      gload_lds16(ag,           As + wv*512 + lane*8);
      gload_lds16(ag + 64*KS,   As + 2048 + wv*512 + lane*8);
      const bf16* bg = B + (size_t)(n0 + wv*16 + srow)*KS + k0 + schk*8;
      gload_lds16(bg,           Bs + wv*512 + lane*8);
      gload_lds16(bg + 64*KS,   Bs + 2048 + wv*512 + lane*8);
    }
    __syncthreads();
    frag8 a[4], b[4];
    #pragma unroll
    for (int mi=0;mi<4;++mi)
      a[mi] = *(const frag8*)(As + (wm*64 + mi*16 + fr)*32 + fq*8);
    #pragma unroll
    for (int ni=0;ni<4;++ni)
      b[ni] = *(const frag8*)(Bs + (wn*64 + ni*16 + fr)*32 + fq*8);
    #pragma unroll
    for (int mi=0;mi<4;++mi)
      #pragma unroll
      for (int ni=0;ni<4;++ni)
        acc[mi][ni] = __builtin_amdgcn_mfma_f32_16x16x32_bf16(a[mi], b[ni], acc[mi][ni], 0, 0, 0);
    __syncthreads();
  }

  // epilogue: C/D layout col=lane&15, row=(lane>>4)*4+reg  [m89/m91-verified]
  #pragma unroll
  for (int mi=0;mi<4;++mi){
    int row = row0 + wm*64 + mi*16 + fq*4;
    #pragma unroll
    for (int ni=0;ni<4;++ni){
      int col = n0 + wn*64 + ni*16 + fr;
      if (EPI == 0){
        if (col < EMB){
          bf16* cp = Cb + (size_t)row*STR + col;
          #pragma unroll
          for (int r=0;r<4;++r)
            cp[(size_t)r*STR] = __float2bfloat16(sigmoidf_(acc[mi][ni][r]));
        }
      } else if (EPI == 1){
        float bv = (col < HID) ? bias[col] : 0.0f;
        bf16* cp = Cb + (size_t)row*HPAD + col;
        #pragma unroll
        for (int r=0;r<4;++r)
          cp[(size_t)r*HPAD] = __float2bfloat16(sigmoidf_(acc[mi][ni][r] + bv));
      } else {
        if (col < HID){
          float bv = bias[col];
          float* cp = Cf + (size_t)row*HID + col;
          #pragma unroll
          for (int r=0;r<4;++r)
            cp[(size_t)r*HID] = sigmoidf_(acc[mi][ni][r] + bv);
        }
      }
    }
  }
}

// ---------------- FC3: out = h2 @ Wc + bc  (wave per batch row) ----------------

__global__ __launch_bounds__(256) void k_fc3(const float* __restrict__ h2,
                                             const float* __restrict__ Wc,
                                             const float* __restrict__ bc,
                                             float* __restrict__ out){
  int w = (int)((blockIdx.x*blockDim.x + threadIdx.x) >> 6);
  int lane = threadIdx.x & 63;
  if (w >= BATCH) return;
  const float* hr = h2 + (size_t)w*HID;
  float a0 = 0.f, a1 = 0.f;
  for (int k = lane; k < HID; k += 64){
    float h = hr[k];
    a0 += h * Wc[k*2+0];
    a1 += h * Wc[k*2+1];
  }
  #pragma unroll
  for (int off = 32; off; off >>= 1){
    a0 += __shfl_down(a0, off);
    a1 += __shfl_down(a1, off);
  }
  if (lane == 0){
    out[w*2+0] = a0 + bc[0];
    out[w*2+1] = a1 + bc[1];
  }
}

// ---------------- launch ----------------

extern "C" void kernel_launch(void* const* d_in, const int* in_sizes, int n_in,
                              void* d_out, int out_size, void* d_ws, size_t ws_size,
                              hipStream_t stream){
  const float* input = (const float*)d_in[0];
  const int*   node  = (const int*)d_in[1];
  const int*   erow  = (const int*)d_in[2];
  const int*   ecol  = (const int*)d_in[3];
  const float* H0    = (const float*)d_in[4];
  const float* W1    = (const float*)d_in[5];
  const float* W2    = (const float*)d_in[6];
  const float* Wa    = (const float*)d_in[7];
  const float* ba    = (const float*)d_in[8];
  const float* Wb    = (const float*)d_in[9];
  const float* bb    = (const float*)d_in[10];
  const float* Wc    = (const float*)d_in[11];
  const float* bc    = (const float*)d_in[12];

  char* p = (char*)d_ws;
  auto alloc = [&](size_t bytes)->char*{ char* r = p; p += (bytes + 255) & ~(size_t)255; return r; };
  int*   deg    = (int*)  alloc((size_t)NVX*4);
  float* dinv   = (float*)alloc((size_t)NVX*4);
  int*   rowptr = (int*)  alloc((size_t)(NVX+1)*4);
  int*   cursor = (int*)  alloc((size_t)NVX*4);
  int*   bsum   = (int*)  alloc((size_t)NB*4);
  int*   boff   = (int*)  alloc((size_t)NB*4);
  int*   ccol   = (int*)  alloc((size_t)NEX*4);
  float* cval   = (float*)alloc((size_t)NEX*4);
  bf16*  G      = (bf16*) alloc((size_t)NVR*STR*2);
  bf16*  Hb     = (bf16*) alloc((size_t)NVR*STR*2);
  bf16*  Wt     = (bf16*) alloc((size_t)NPAD*STR*2);
  bf16*  Afc    = (bf16*) alloc((size_t)BATCH*FCK*2);
  bf16*  Wat    = (bf16*) alloc((size_t)HPAD*FCK*2);
  bf16*  Wbt    = (bf16*) alloc((size_t)HPAD*HPAD*2);
  bf16*  h1     = (bf16*) alloc((size_t)BATCH*HPAD*2);
  float* h2     = (float*)alloc((size_t)BATCH*HID*4);

  hipMemsetAsync(deg, 0, (size_t)NVX*4, stream);
  k_deg     <<<(NEX+255)/256, 256, 0, stream>>>(erow, deg);
  k_dinv    <<<(NVX+255)/256, 256, 0, stream>>>(deg, dinv);
  k_partsum <<<NB, 256, 0, stream>>>(deg, bsum);
  k_scanb   <<<1, 512, 0, stream>>>(bsum, boff, rowptr);
  k_writeptr<<<NB, 256, 0, stream>>>(deg, boff, rowptr, cursor);
  k_scatter <<<(NEX+255)/256, 256, 0, stream>>>(erow, ecol, dinv, cursor, ccol, cval);

  // weight prep (bf16, transposed, padded)
  k_prepW<<<(NPAD*STR+255)/256, 256, 0, stream>>>(W1, Wt, EMB, EMB, STR, NPAD);
  k_prepW<<<(HPAD*FCK+255)/256, 256, 0, stream>>>(Wa, Wat, EMB+IN_DIM, HID, FCK, HPAD);
  k_prepW<<<(HPAD*HPAD+255)/256, 256, 0, stream>>>(Wb, Wbt, HID, HID, HPAD, HPAD);

  dim3 ggrid(NPAD/128, NVR/128);

  // G1 = LM @ H0 ; H1 = sigmoid(G1 @ W1)   (associativity: LM@(H0@W1) == (LM@H0)@W1)
  k_spmm<float><<<NVR/4, 256, 0, stream>>>(rowptr, ccol, cval, H0, EMB, G);
  k_mfma_gemm<STR,0><<<ggrid, 256, 0, stream>>>(G, Wt, Hb, nullptr, nullptr);
  // G2 = LM @ H1 ; H2 = sigmoid(G2 @ W2)
  k_prepW<<<(NPAD*STR+255)/256, 256, 0, stream>>>(W2, Wt, EMB, EMB, STR, NPAD);
  k_spmm<bf16> <<<NVR/4, 256, 0, stream>>>(rowptr, ccol, cval, Hb, STR, G);
  k_mfma_gemm<STR,0><<<ggrid, 256, 0, stream>>>(G, Wt, Hb, nullptr, nullptr);

  // FC stack (MFMA)
  k_prepA<<<dim3((FCK+255)/256, BATCH), 256, 0, stream>>>(Hb, node, input, Afc);
  k_mfma_gemm<FCK,1><<<dim3(HPAD/128, BATCH/128), 256, 0, stream>>>(Afc, Wat, h1, nullptr, ba);
  k_mfma_gemm<HPAD,2><<<dim3(HPAD/128, BATCH/128), 256, 0, stream>>>(h1, Wbt, nullptr, h2, bb);
  k_fc3<<<BATCH/4, 256, 0, stream>>>(h2, Wc, bc, (float*)d_out);
}

// Round 5
// 597.620 us; speedup vs baseline: 2.7129x; 1.1391x over previous
//
#include <hip/hip_runtime.h>
#include <hip/hip_bf16.h>

typedef __hip_bfloat16 bf16;

#define NVX 117000
#define NVR 117120         // rows padded to multiple of 128 (= 915*128)
#define NEX 468000
#define EMB 300
#define STR 320            // padded K/row stride for bf16 node buffers (pads zeroed)
#define NPAD 384           // padded N for node GEMM (3 tiles of 128)
#define IN_DIM 768
#define BATCH 4096
#define HID 500
#define FCK 1088           // FC1 K padded (300+768=1068 -> 34*32)
#define HPAD 512           // FC hidden padded
#define NB 458             // scan blocks: ceil(NVX/256)

typedef __attribute__((ext_vector_type(8))) short frag8;   // 8 bf16 (4 VGPRs)
typedef __attribute__((ext_vector_type(4))) float f32x4;   // 4 fp32 acc

__device__ __forceinline__ float sigmoidf_(float x){ return 1.0f/(1.0f + __expf(-x)); }
__device__ __forceinline__ float bfs2f(short s){
  return __uint_as_float(((unsigned int)(unsigned short)s) << 16);
}
__device__ __forceinline__ short f2bfs(float f){
  bf16 b = __float2bfloat16(f);
  return *(short*)&b;
}

__device__ __forceinline__ void gload_lds16(const bf16* g, bf16* l){
  __builtin_amdgcn_global_load_lds((const __attribute__((address_space(1))) void*)g,
                                   (__attribute__((address_space(3))) void*)l, 16, 0, 0);
}

// ---------------- graph preprocessing ----------------

__global__ void k_deg(const int* __restrict__ erow, int* __restrict__ deg){
  int i = blockIdx.x*blockDim.x + threadIdx.x;
  if (i < NEX) atomicAdd(&deg[erow[i]], 1);
}

__global__ void k_dinv(const int* __restrict__ deg, float* __restrict__ dinv){
  int i = blockIdx.x*blockDim.x + threadIdx.x;
  if (i < NVX){ int d = deg[i]; dinv[i] = d > 0 ? rsqrtf((float)d) : 0.0f; }
}

// hierarchical exclusive scan of deg -> rowptr (+cursor copy)
__global__ __launch_bounds__(256) void k_partsum(const int* __restrict__ deg,
                                                 int* __restrict__ bsum){
  __shared__ int s[256];
  int t = threadIdx.x;
  int i = blockIdx.x*256 + t;
  s[t] = (i < NVX) ? deg[i] : 0;
  __syncthreads();
  #pragma unroll
  for (int off=128; off; off>>=1){
    if (t < off) s[t] += s[t+off];
    __syncthreads();
  }
  if (t == 0) bsum[blockIdx.x] = s[0];
}

__global__ __launch_bounds__(512) void k_scanb(const int* __restrict__ bsum,
                                               int* __restrict__ boff,
                                               int* __restrict__ rowptr){
  __shared__ int s[512];
  int t = threadIdx.x;
  int v = (t < NB) ? bsum[t] : 0;
  s[t] = v; __syncthreads();
  #pragma unroll
  for (int off=1; off<512; off<<=1){
    int u = (t>=off) ? s[t-off] : 0;
    __syncthreads();
    s[t] += u;
    __syncthreads();
  }
  if (t < NB) boff[t] = s[t] - v;        // exclusive block offsets
  if (t == 511) rowptr[NVX] = s[511];    // total
}

__global__ __launch_bounds__(256) void k_writeptr(const int* __restrict__ deg,
                                                  const int* __restrict__ boff,
                                                  int* __restrict__ rowptr,
                                                  int* __restrict__ cursor){
  __shared__ int s[256];
  int t = threadIdx.x;
  int i = blockIdx.x*256 + t;
  int v = (i < NVX) ? deg[i] : 0;
  s[t] = v; __syncthreads();
  #pragma unroll
  for (int off=1; off<256; off<<=1){
    int u = (t>=off) ? s[t-off] : 0;
    __syncthreads();
    s[t] += u;
    __syncthreads();
  }
  if (i < NVX){
    int e = boff[blockIdx.x] + s[t] - v;  // exclusive prefix
    rowptr[i] = e;
    cursor[i] = e;
  }
}

__global__ void k_scatter(const int* __restrict__ erow, const int* __restrict__ ecol,
                          const float* __restrict__ dinv, int* __restrict__ cursor,
                          int* __restrict__ ccol, float* __restrict__ cval){
  int i = blockIdx.x*blockDim.x + threadIdx.x;
  if (i < NEX){
    int r = erow[i], c = ecol[i];
    int p = atomicAdd(&cursor[r], 1);
    ccol[p] = c;
    cval[p] = dinv[r]*dinv[c];
  }
}

// H0 (f32 [NVX,300]) -> Xs (bf16 [NVR,320], pads zero). 4 cols per thread.
__global__ __launch_bounds__(256) void k_prepH(const float* __restrict__ H0,
                                               bf16* __restrict__ Xs){
  int i = blockIdx.x*256 + threadIdx.x;      // i = r*80 + g, g = col/4
  if (i >= NVR*80) return;
  int r = i / 80, g = i % 80;
  int c = g*4;
  short4 o;
  if (r < NVX && c < EMB){
    float4 v = *(const float4*)(H0 + (size_t)r*EMB + c);
    o.x = f2bfs(v.x); o.y = f2bfs(v.y); o.z = f2bfs(v.z); o.w = f2bfs(v.w);
  } else {
    o.x = o.y = o.z = o.w = 0;  // +0.0f bf16 == bit pattern 0
  }
  *(short4*)(Xs + (size_t)r*STR + c) = o;
}

// W (f32, [kdim, ndim] k-major) -> Wt (bf16, [npad][kpad] n-major, zero-padded)
__global__ void k_prepW(const float* __restrict__ W, bf16* __restrict__ Wt,
                        int kdim, int ndim, int kpad, int npad){
  int i = blockIdx.x*blockDim.x + threadIdx.x;
  if (i >= npad*kpad) return;
  int n = i / kpad, k = i % kpad;
  float v = (n < ndim && k < kdim) ? W[k*ndim + n] : 0.0f;
  Wt[i] = __float2bfloat16(v);
}

// Afc[r][k] = H2[node[r]][k] (k<300) | input[r][k-300] (k<1068) | 0
__global__ __launch_bounds__(256) void k_prepA(const bf16* __restrict__ H2,
                                               const int* __restrict__ node,
                                               const float* __restrict__ input,
                                               bf16* __restrict__ Afc){
  int k = blockIdx.x*256 + threadIdx.x;
  int r = blockIdx.y;
  if (k >= FCK) return;
  bf16 v;
  if (k < EMB)           v = H2[(size_t)node[r]*STR + k];
  else if (k < EMB+IN_DIM) v = __float2bfloat16(input[(size_t)r*IN_DIM + (k - EMB)]);
  else                   v = __float2bfloat16(0.0f);
  Afc[(size_t)r*FCK + k] = v;
}

// ---------------- spmm (vectorized): Y[v,:] = sum_e val * X[col(e),:] ----------------
// wave per row; lanes 0..39 each own 8 contiguous cols (16 B vector load per edge).
// X pad cols are zero => Y pads come out zero automatically; pad rows write zero.

__global__ __launch_bounds__(256) void k_spmm_v(const int* __restrict__ rowptr,
                                                const int* __restrict__ ccol,
                                                const float* __restrict__ cval,
                                                const bf16* __restrict__ X,
                                                bf16* __restrict__ Y){
  int w = (int)((blockIdx.x*blockDim.x + threadIdx.x) >> 6);
  int lane = threadIdx.x & 63;
  if (w >= NVR || lane >= 40) return;
  float acc[8] = {0.f,0.f,0.f,0.f,0.f,0.f,0.f,0.f};
  if (w < NVX){
    int e0 = rowptr[w], e1 = rowptr[w+1];
    int e = e0;
    for (; e + 1 < e1; e += 2){
      float v0 = cval[e], v1 = cval[e+1];
      frag8 x0 = *(const frag8*)(X + (size_t)ccol[e]*STR + lane*8);
      frag8 x1 = *(const frag8*)(X + (size_t)ccol[e+1]*STR + lane*8);
      #pragma unroll
      for (int j=0;j<8;++j) acc[j] += v0 * bfs2f(x0[j]);
      #pragma unroll
      for (int j=0;j<8;++j) acc[j] += v1 * bfs2f(x1[j]);
    }
    if (e < e1){
      float v0 = cval[e];
      frag8 x0 = *(const frag8*)(X + (size_t)ccol[e]*STR + lane*8);
      #pragma unroll
      for (int j=0;j<8;++j) acc[j] += v0 * bfs2f(x0[j]);
    }
  }
  frag8 o;
  #pragma unroll
  for (int j=0;j<8;++j) o[j] = f2bfs(acc[j]);
  *(frag8*)(Y + (size_t)w*STR + lane*8) = o;
}

// ---------------- generic 128x128 MFMA GEMM, compile-time K, epilogue select ----------------
// grid = (Ncols/128, Mrows/128). A [M][KS] bf16, B [N][KS] bf16 (n-major).
// EPI 0: node gemm  -> Cb bf16 stride STR, sigmoid, cols < EMB only
// EPI 1: FC1        -> Cb bf16 stride HPAD, sigmoid(acc + bias[col<HID?]), all cols
// EPI 2: FC2        -> Cf f32  stride HID, sigmoid(acc + bias), cols < HID only

template<int KS, int EPI>
__global__ __launch_bounds__(256) void k_mfma_gemm(const bf16* __restrict__ A,
                                                   const bf16* __restrict__ B,
                                                   bf16* __restrict__ Cb,
                                                   float* __restrict__ Cf,
                                                   const float* __restrict__ bias){
  __shared__ bf16 As[128*32];
  __shared__ bf16 Bs[128*32];
  const int tid  = threadIdx.x;
  const int wv   = tid >> 6;
  const int lane = tid & 63;
  const int row0 = blockIdx.y * 128;
  const int n0   = blockIdx.x * 128;
  const int wm = wv & 1, wn = wv >> 1;

  f32x4 acc[4][4];
  #pragma unroll
  for (int i=0;i<4;++i)
    #pragma unroll
    for (int j=0;j<4;++j) acc[i][j] = (f32x4)(0.0f);

  const int srow = lane >> 2;     // 0..15 staging row within wave stripe
  const int schk = lane & 3;      // 16B chunk within 64B (=32 bf16) row
  const int fr = lane & 15;       // fragment row/col index
  const int fq = lane >> 4;       // quad -> k offset = fq*8

  for (int k0 = 0; k0 < KS; k0 += 32){
    {
      const bf16* ag = A + (size_t)(row0 + wv*16 + srow)*KS + k0 + schk*8;
      gload_lds16(ag,           As + wv*512 + lane*8);
      gload_lds16(ag + 64*KS,   As + 2048 + wv*512 + lane*8);
      const bf16* bg = B + (size_t)(n0 + wv*16 + srow)*KS + k0 + schk*8;
      gload_lds16(bg,           Bs + wv*512 + lane*8);
      gload_lds16(bg + 64*KS,   Bs + 2048 + wv*512 + lane*8);
    }
    __syncthreads();
    frag8 a[4], b[4];
    #pragma unroll
    for (int mi=0;mi<4;++mi)
      a[mi] = *(const frag8*)(As + (wm*64 + mi*16 + fr)*32 + fq*8);
    #pragma unroll
    for (int ni=0;ni<4;++ni)
      b[ni] = *(const frag8*)(Bs + (wn*64 + ni*16 + fr)*32 + fq*8);
    #pragma unroll
    for (int mi=0;mi<4;++mi)
      #pragma unroll
      for (int ni=0;ni<4;++ni)
        acc[mi][ni] = __builtin_amdgcn_mfma_f32_16x16x32_bf16(a[mi], b[ni], acc[mi][ni], 0, 0, 0);
    __syncthreads();
  }

  // epilogue: C/D layout col=lane&15, row=(lane>>4)*4+reg  [m89/m91-verified]
  #pragma unroll
  for (int mi=0;mi<4;++mi){
    int row = row0 + wm*64 + mi*16 + fq*4;
    #pragma unroll
    for (int ni=0;ni<4;++ni){
      int col = n0 + wn*64 + ni*16 + fr;
      if (EPI == 0){
        if (col < EMB){
          bf16* cp = Cb + (size_t)row*STR + col;
          #pragma unroll
          for (int r=0;r<4;++r)
            cp[(size_t)r*STR] = __float2bfloat16(sigmoidf_(acc[mi][ni][r]));
        }
      } else if (EPI == 1){
        float bv = (col < HID) ? bias[col] : 0.0f;
        bf16* cp = Cb + (size_t)row*HPAD + col;
        #pragma unroll
        for (int r=0;r<4;++r)
          cp[(size_t)r*HPAD] = __float2bfloat16(sigmoidf_(acc[mi][ni][r] + bv));
      } else {
        if (col < HID){
          float bv = bias[col];
          float* cp = Cf + (size_t)row*HID + col;
          #pragma unroll
          for (int r=0;r<4;++r)
            cp[(size_t)r*HID] = sigmoidf_(acc[mi][ni][r] + bv);
        }
      }
    }
  }
}

// ---------------- FC3: out = h2 @ Wc + bc  (wave per batch row) ----------------

__global__ __launch_bounds__(256) void k_fc3(const float* __restrict__ h2,
                                             const float* __restrict__ Wc,
                                             const float* __restrict__ bc,
                                             float* __restrict__ out){
  int w = (int)((blockIdx.x*blockDim.x + threadIdx.x) >> 6);
  int lane = threadIdx.x & 63;
  if (w >= BATCH) return;
  const float* hr = h2 + (size_t)w*HID;
  float a0 = 0.f, a1 = 0.f;
  for (int k = lane; k < HID; k += 64){
    float h = hr[k];
    a0 += h * Wc[k*2+0];
    a1 += h * Wc[k*2+1];
  }
  #pragma unroll
  for (int off = 32; off; off >>= 1){
    a0 += __shfl_down(a0, off);
    a1 += __shfl_down(a1, off);
  }
  if (lane == 0){
    out[w*2+0] = a0 + bc[0];
    out[w*2+1] = a1 + bc[1];
  }
}

// ---------------- launch ----------------

extern "C" void kernel_launch(void* const* d_in, const int* in_sizes, int n_in,
                              void* d_out, int out_size, void* d_ws, size_t ws_size,
                              hipStream_t stream){
  const float* input = (const float*)d_in[0];
  const int*   node  = (const int*)d_in[1];
  const int*   erow  = (const int*)d_in[2];
  const int*   ecol  = (const int*)d_in[3];
  const float* H0    = (const float*)d_in[4];
  const float* W1    = (const float*)d_in[5];
  const float* W2    = (const float*)d_in[6];
  const float* Wa    = (const float*)d_in[7];
  const float* ba    = (const float*)d_in[8];
  const float* Wb    = (const float*)d_in[9];
  const float* bb    = (const float*)d_in[10];
  const float* Wc    = (const float*)d_in[11];
  const float* bc    = (const float*)d_in[12];

  char* p = (char*)d_ws;
  auto alloc = [&](size_t bytes)->char*{ char* r = p; p += (bytes + 255) & ~(size_t)255; return r; };
  int*   deg    = (int*)  alloc((size_t)NVX*4);
  float* dinv   = (float*)alloc((size_t)NVX*4);
  int*   rowptr = (int*)  alloc((size_t)(NVX+1)*4);
  int*   cursor = (int*)  alloc((size_t)NVX*4);
  int*   bsum   = (int*)  alloc((size_t)NB*4);
  int*   boff   = (int*)  alloc((size_t)NB*4);
  int*   ccol   = (int*)  alloc((size_t)NEX*4);
  float* cval   = (float*)alloc((size_t)NEX*4);
  bf16*  G      = (bf16*) alloc((size_t)NVR*STR*2);
  bf16*  Hb     = (bf16*) alloc((size_t)NVR*STR*2);
  bf16*  Wt     = (bf16*) alloc((size_t)NPAD*STR*2);
  bf16*  Afc    = (bf16*) alloc((size_t)BATCH*FCK*2);
  bf16*  Wat    = (bf16*) alloc((size_t)HPAD*FCK*2);
  bf16*  Wbt    = (bf16*) alloc((size_t)HPAD*HPAD*2);
  bf16*  h1     = (bf16*) alloc((size_t)BATCH*HPAD*2);
  float* h2     = (float*)alloc((size_t)BATCH*HID*4);

  bf16* Xs = Hb;   // H0-as-bf16 lives in Hb: dead once spmm1 reads it, before gemm1 writes Hb

  hipMemsetAsync(deg, 0, (size_t)NVX*4, stream);
  k_deg     <<<(NEX+255)/256, 256, 0, stream>>>(erow, deg);
  k_dinv    <<<(NVX+255)/256, 256, 0, stream>>>(deg, dinv);
  k_partsum <<<NB, 256, 0, stream>>>(deg, bsum);
  k_scanb   <<<1, 512, 0, stream>>>(bsum, boff, rowptr);
  k_writeptr<<<NB, 256, 0, stream>>>(deg, boff, rowptr, cursor);
  k_scatter <<<(NEX+255)/256, 256, 0, stream>>>(erow, ecol, dinv, cursor, ccol, cval);
  k_prepH   <<<(NVR*80+255)/256, 256, 0, stream>>>(H0, Xs);

  // weight prep (bf16, transposed, padded)
  k_prepW<<<(NPAD*STR+255)/256, 256, 0, stream>>>(W1, Wt, EMB, EMB, STR, NPAD);
  k_prepW<<<(HPAD*FCK+255)/256, 256, 0, stream>>>(Wa, Wat, EMB+IN_DIM, HID, FCK, HPAD);
  k_prepW<<<(HPAD*HPAD+255)/256, 256, 0, stream>>>(Wb, Wbt, HID, HID, HPAD, HPAD);

  dim3 ggrid(NPAD/128, NVR/128);

  // G1 = LM @ H0 ; H1 = sigmoid(G1 @ W1)   (associativity: LM@(H0@W1) == (LM@H0)@W1)
  k_spmm_v<<<NVR/4, 256, 0, stream>>>(rowptr, ccol, cval, Xs, G);
  k_mfma_gemm<STR,0><<<ggrid, 256, 0, stream>>>(G, Wt, Hb, nullptr, nullptr);
  // G2 = LM @ H1 ; H2 = sigmoid(G2 @ W2)
  k_prepW<<<(NPAD*STR+255)/256, 256, 0, stream>>>(W2, Wt, EMB, EMB, STR, NPAD);
  k_spmm_v<<<NVR/4, 256, 0, stream>>>(rowptr, ccol, cval, Hb, G);
  k_mfma_gemm<STR,0><<<ggrid, 256, 0, stream>>>(G, Wt, Hb, nullptr, nullptr);

  // FC stack (MFMA)
  k_prepA<<<dim3((FCK+255)/256, BATCH), 256, 0, stream>>>(Hb, node, input, Afc);
  k_mfma_gemm<FCK,1><<<dim3(HPAD/128, BATCH/128), 256, 0, stream>>>(Afc, Wat, h1, nullptr, ba);
  k_mfma_gemm<HPAD,2><<<dim3(HPAD/128, BATCH/128), 256, 0, stream>>>(h1, Wbt, nullptr, h2, bb);
  k_fc3<<<BATCH/4, 256, 0, stream>>>(h2, Wc, bc, (float*)d_out);
}